// Round 5
// baseline (308.833 us; speedup 1.0000x reference)
//
#include <hip/hip_runtime.h>
#include <hip/hip_bf16.h>
#include <stdint.h>

#define N_NODES 100000
#define DEG 16
#define D_IN 128
#define D_OUT 256
#define K_TOP 32
#define K_CAT 256   // concatenated K = D_IN(self) + D_IN(neigh)

typedef __attribute__((ext_vector_type(8))) short short8;
typedef __attribute__((ext_vector_type(4))) float floatx4;

__device__ __forceinline__ unsigned pack_bf16_rne(float f) {
    union { float f; unsigned u; } c; c.f = f;
    unsigned u = c.u;
    return (u + 0x7fffu + ((u >> 16) & 1u)) >> 16;   // round-to-nearest-even
}
__device__ __forceinline__ float bf16lo_to_f(unsigned lo16) {
    union { unsigned u; float f; } c; c.u = lo16 << 16; return c.f;
}

// ---------------- kernel 1: pack [w_self | w_neigh] -> bf16 B[256][256] ----------------
__global__ __launch_bounds__(256) void k_packw(const float* __restrict__ w_self,
                                               const float* __restrict__ w_neigh,
                                               unsigned short* __restrict__ bmat) {
    int o = blockIdx.x;      // 0..255 output channel
    int k = threadIdx.x;     // 0..255 concat-K
    float v = (k < D_IN) ? w_self[o * D_IN + k] : w_neigh[o * D_IN + (k - D_IN)];
    bmat[o * K_CAT + k] = (unsigned short)pack_bf16_rne(v);
}

// ------------- kernel 2: densify via LDS ds_add_f32 scatter -> bf16 x[N][128] ----------
#define DROWS 64
__global__ __launch_bounds__(256) void k_densify(const float* __restrict__ topk_v,
                                                 const int* __restrict__ topk_i,
                                                 unsigned short* __restrict__ xbf) {
    __shared__ float sx[DROWS * D_IN];   // 32 KiB
    const int t = threadIdx.x;
    const int row0 = blockIdx.x * DROWS;

    #pragma unroll
    for (int p = 0; p < 8; ++p)
        *(floatx4*)&sx[(t + p * 256) * 4] = (floatx4){0.f, 0.f, 0.f, 0.f};
    __syncthreads();

    const size_t tbase = (size_t)row0 * K_TOP;
    #pragma unroll
    for (int p = 0; p < 8; ++p) {
        int q = t + p * 256;             // 0..2047
        int r = q >> 5;                  // 0..63
        if (row0 + r < N_NODES) {
            int   ci = topk_i[tbase + q];
            float cv = topk_v[tbase + q];
            atomicAdd(&sx[r * D_IN + ci], cv);   // ds_add_f32, no return
        }
    }
    __syncthreads();

    #pragma unroll
    for (int p = 0; p < 16; ++p) {
        int d = t + p * 256;             // dword index 0..4095
        int r = d >> 6;                  // 0..63
        int c2 = (d & 63) * 2;
        if (row0 + r < N_NODES) {
            float2 v = *(const float2*)&sx[r * D_IN + c2];
            ((unsigned*)(xbf + (size_t)(row0 + r) * D_IN))[d & 63] =
                pack_bf16_rne(v.x) | (pack_bf16_rne(v.y) << 16);
        }
    }
}

// -------- kernel 3: FUSED SpMM + GEMM.  out[N][256] = [feat|S.x] @ B^T + bias ----------
// 64-row blocks. A-tile built in LDS: left half = feat fp32->bf16 staged coalesced,
// right half = edge-weighted gather of xbf rows (half-wave per row, 16 outstanding
// gathers). Then K=256 MFMA loop (4 waves, 64x64 cols each). abf never materialized.
#define BM 64
#define BK 32
#define LDA 264   // shorts; 528 B row stride = 16B-aligned, bank shift 4 -> 2-way (free)
#define LDB 40    // shorts; 80 B row stride (round-4 proven)

__global__ __launch_bounds__(256, 3) void k_fused(const float* __restrict__ feat,
                                                  const float* __restrict__ csr_w,
                                                  const int* __restrict__ col_idx,
                                                  const unsigned short* __restrict__ xbf,
                                                  const unsigned short* __restrict__ bmat,
                                                  const float* __restrict__ bias,
                                                  float* __restrict__ out) {
    __shared__ unsigned short As[BM * LDA];   // 33 KiB: cols 0..127 feat, 128..255 agg
    __shared__ unsigned short Bs[D_OUT * LDB];// 20 KiB
    const int t = threadIdx.x;
    const int lane = t & 63, wave = t >> 6;
    const int row0 = blockIdx.x * BM;
    const int quad = lane >> 4, l16 = lane & 15;
    const int hw = t >> 5, hl = t & 31;      // half-wave id 0..7, half-lane 0..31

    // edge (col,weight) loads for this block's 64 rows: 8 rows per half-wave
    int   ce[8]; float we_[8];
    #pragma unroll
    for (int it = 0; it < 8; ++it) {
        int gr = row0 + hw * 8 + it;
        ce[it] = 0; we_[it] = 0.f;
        if (hl < DEG && gr < N_NODES) {
            ce[it] = col_idx[gr * DEG + hl];
            we_[it] = csr_w[gr * DEG + hl];
        }
    }

    // stage A-left: feat fp32 -> bf16 (2048 float4 chunks, 8 per thread)
    #pragma unroll
    for (int p = 0; p < 8; ++p) {
        int q = t + p * 256;             // 0..2047
        int r = q >> 5;                  // 0..63
        int c4 = (q & 31) * 4;           // 0..124
        uint2 pk = {0u, 0u};
        if (row0 + r < N_NODES) {
            float4 f = *(const float4*)(feat + (size_t)(row0 + r) * D_IN + c4);
            pk.x = pack_bf16_rne(f.x) | (pack_bf16_rne(f.y) << 16);
            pk.y = pack_bf16_rne(f.z) | (pack_bf16_rne(f.w) << 16);
        }
        *(uint2*)&As[r * LDA + c4] = pk;
    }

    // stage B chunk kt=0
    #pragma unroll
    for (int p = 0; p < 4; ++p) {
        int chunk = t + p * 256;
        int r  = chunk >> 2;             // 0..255
        int ko = (chunk & 3) * 8;
        *(uint4*)&Bs[r * LDB + ko] = *(const uint4*)(bmat + (size_t)r * K_CAT + ko);
    }

    // gather + aggregate -> A-right (agg cols 128..255)
    const int bsel = lane & 32;
    #pragma unroll
    for (int it = 0; it < 8; ++it) {
        int r = hw * 8 + it;
        uint2 vv[DEG];
        #pragma unroll
        for (int e = 0; e < DEG; ++e) {
            int col = __shfl(ce[it], bsel | e);
            vv[e] = *(const uint2*)(xbf + (size_t)col * D_IN + hl * 4);
        }
        float a0 = 0.f, a1 = 0.f, a2 = 0.f, a3 = 0.f;
        #pragma unroll
        for (int e = 0; e < DEG; ++e) {
            float w = __shfl(we_[it], bsel | e);
            a0 += w * bf16lo_to_f(vv[e].x & 0xffffu);
            a1 += w * bf16lo_to_f(vv[e].x >> 16);
            a2 += w * bf16lo_to_f(vv[e].y & 0xffffu);
            a3 += w * bf16lo_to_f(vv[e].y >> 16);
        }
        uint2 pk;
        pk.x = pack_bf16_rne(a0) | (pack_bf16_rne(a1) << 16);
        pk.y = pack_bf16_rne(a2) | (pack_bf16_rne(a3) << 16);
        *(uint2*)&As[r * LDA + D_IN + hl * 4] = pk;
    }

    floatx4 acc[4][4];
    #pragma unroll
    for (int i = 0; i < 4; ++i)
        #pragma unroll
        for (int j = 0; j < 4; ++j)
            acc[i][j] = (floatx4){0.f, 0.f, 0.f, 0.f};

    __syncthreads();

    for (int kt = 0; kt < K_CAT; kt += BK) {
        if (kt) {
            __syncthreads();
            #pragma unroll
            for (int p = 0; p < 4; ++p) {
                int chunk = t + p * 256;
                int r  = chunk >> 2;
                int ko = (chunk & 3) * 8;
                *(uint4*)&Bs[r * LDB + ko] = *(const uint4*)(bmat + (size_t)r * K_CAT + kt + ko);
            }
            __syncthreads();
        }
        short8 afr[4], bfr[4];
        #pragma unroll
        for (int i = 0; i < 4; ++i) {
            int m = i * 16 + l16;            // A frag: m=lane&15, k=quad*8+j
            afr[i] = *(const short8*)&As[m * LDA + kt + quad * 8];
        }
        #pragma unroll
        for (int j = 0; j < 4; ++j) {
            int n = wave * 64 + j * 16 + l16; // B frag: n=lane&15, k=quad*8+j
            bfr[j] = *(const short8*)&Bs[n * LDB + quad * 8];
        }
        #pragma unroll
        for (int i = 0; i < 4; ++i)
            #pragma unroll
            for (int j = 0; j < 4; ++j)
                acc[i][j] = __builtin_amdgcn_mfma_f32_16x16x32_bf16(afr[i], bfr[j], acc[i][j], 0, 0, 0);
    }

    // epilogue: D frag mapping col=lane&15, row=quad*4+reg
    #pragma unroll
    for (int j = 0; j < 4; ++j) {
        int cg = wave * 64 + j * 16 + l16;
        float bv = bias[cg];
        #pragma unroll
        for (int i = 0; i < 4; ++i) {
            int mbase = row0 + i * 16 + quad * 4;
            #pragma unroll
            for (int rr = 0; rr < 4; ++rr) {
                int gr = mbase + rr;
                if (gr < N_NODES) out[(size_t)gr * D_OUT + cg] = acc[i][j][rr] + bv;
            }
        }
    }
}

extern "C" void kernel_launch(void* const* d_in, const int* in_sizes, int n_in,
                              void* d_out, int out_size, void* d_ws, size_t ws_size,
                              hipStream_t stream) {
    const float* feat    = (const float*)d_in[0];
    const float* topk_v  = (const float*)d_in[1];
    const float* csr_w   = (const float*)d_in[2];
    const float* w_neigh = (const float*)d_in[3];
    const float* w_self  = (const float*)d_in[4];
    const float* b_self  = (const float*)d_in[5];
    const int*   topk_i  = (const int*)d_in[6];
    // d_in[7] = indptr (fixed degree 16, unused), d_in[8] = indices
    const int*   indices = (const int*)d_in[8];
    float* out = (float*)d_out;

    // workspace layout (bf16): x[N*128] | B[256*256]  (~25.7 MB)
    unsigned short* xbf  = (unsigned short*)d_ws;
    unsigned short* bmat = xbf + (size_t)N_NODES * D_IN;

    k_packw<<<dim3(256), dim3(256), 0, stream>>>(w_self, w_neigh, bmat);
    k_densify<<<dim3((N_NODES + DROWS - 1) / DROWS), dim3(256), 0, stream>>>(topk_v, topk_i, xbf);
    k_fused<<<dim3((N_NODES + BM - 1) / BM), dim3(256), 0, stream>>>(feat, csr_w, indices, xbf, bmat, b_self, out);
}